// Round 9
// baseline (915.725 us; speedup 1.0000x reference)
//
#include <hip/hip_runtime.h>
#include <math.h>

#define HN 128
#define NC 8
#define EPSV 1e-5f
#define SLOPEV 0.01f

typedef __attribute__((ext_vector_type(4))) float f32x4;
typedef __attribute__((ext_vector_type(8))) short bf16x8;

__device__ __forceinline__ uint bf16rne(float f) {
    uint u = __float_as_uint(f);
    return (u + 0x7fffu + ((u >> 16) & 1u)) >> 16;
}

__device__ __forceinline__ int xcc_id() {
    int x;
    asm volatile("s_getreg_b32 %0, hwreg(HW_REG_XCC_ID)" : "=s"(x));
    return x & 7;
}

// ---------------- rank: per-XCD degO slices + device-scope in-count (rank) ----------------
__global__ __launch_bounds__(256) void rank_kernel(
        const int* __restrict__ src, const int* __restrict__ dst,
        int* __restrict__ degO8, int* __restrict__ cntI,
        int* __restrict__ rnk, int E, int n) {
    int* myDeg = degO8 + (size_t)xcc_id() * n;
    int base = blockIdx.x * 1024 + threadIdx.x;
    int s[4], d[4], r[4];
    #pragma unroll
    for (int k = 0; k < 4; k++) {
        int e = base + k * 256;
        if (e < E) { s[k] = src[e]; d[k] = dst[e]; }
    }
    #pragma unroll
    for (int k = 0; k < 4; k++) {
        int e = base + k * 256;
        if (e < E)
            __hip_atomic_fetch_add(&myDeg[s[k]], 1, __ATOMIC_RELAXED,
                                   __HIP_MEMORY_SCOPE_WORKGROUP);   // local-L2 atomic
    }
    #pragma unroll
    for (int k = 0; k < 4; k++) {
        int e = base + k * 256;
        if (e < E) r[k] = atomicAdd(&cntI[d[k]], 1);                // device scope (rank)
    }
    #pragma unroll
    for (int k = 0; k < 4; k++) {
        int e = base + k * 256;
        if (e < E) rnk[e] = r[k];
    }
}

// ---------------- hierarchical exclusive scan ----------------
__global__ __launch_bounds__(256) void scan_partial(const int* __restrict__ degI,
                                                    int* __restrict__ blockSums, int n) {
    __shared__ int sS[256];
    int tid = threadIdx.x;
    int base = blockIdx.x * 1024 + tid * 4;
    int s = 0;
    #pragma unroll
    for (int j = 0; j < 4; j++) {
        int idx = base + j;
        s += (idx < n) ? degI[idx] : 0;
    }
    sS[tid] = s;
    __syncthreads();
    for (int off = 128; off; off >>= 1) {
        if (tid < off) sS[tid] += sS[tid + off];
        __syncthreads();
    }
    if (tid == 0) blockSums[blockIdx.x] = sS[0];
}

__global__ __launch_bounds__(1024) void scan_blocksums(int* __restrict__ blockSums, int nb) {
    __shared__ int sS[1024];
    int tid = threadIdx.x;
    int v = (tid < nb) ? blockSums[tid] : 0;
    sS[tid] = v;
    __syncthreads();
    for (int off = 1; off < 1024; off <<= 1) {
        int t = (tid >= off) ? sS[tid - off] : 0;
        __syncthreads();
        sS[tid] += t;
        __syncthreads();
    }
    if (tid < nb) blockSums[tid] = sS[tid] - v;
}

// local scan + block offset -> row_ptr; sums degO8 slices; computes norms
__global__ __launch_bounds__(256) void scan_final(const int* __restrict__ degI,
                                                  const int* __restrict__ degO8,
                                                  const int* __restrict__ blockSums,
                                                  int* __restrict__ row_ptr,
                                                  float* __restrict__ onorm,
                                                  float* __restrict__ inorm, int n, int E) {
    __shared__ int sS[256];
    int tid = threadIdx.x;
    int base = blockIdx.x * 1024 + tid * 4;
    int v[4];
    int tot = 0;
    #pragma unroll
    for (int j = 0; j < 4; j++) {
        int idx = base + j;
        int vv = (idx < n) ? degI[idx] : 0;
        v[j] = tot;
        tot += vv;
    }
    sS[tid] = tot;
    __syncthreads();
    for (int off = 1; off < 256; off <<= 1) {
        int t = (tid >= off) ? sS[tid - off] : 0;
        __syncthreads();
        sS[tid] += t;
        __syncthreads();
    }
    int tb = blockSums[blockIdx.x] + sS[tid] - tot;
    #pragma unroll
    for (int j = 0; j < 4; j++) {
        int idx = base + j;
        if (idx < n) {
            row_ptr[idx] = tb + v[j];
            int dsum = 0;
            #pragma unroll
            for (int s8 = 0; s8 < 8; s8++) dsum += degO8[(size_t)s8 * n + idx];
            float a = (float)dsum; if (a < 1.f) a = 1.f;
            float b = (float)degI[idx]; if (b < 1.f) b = 1.f;
            onorm[idx] = rsqrtf(a);
            inorm[idx] = rsqrtf(b);
        }
    }
    if (blockIdx.x == 0 && tid == 0) row_ptr[n] = E;
}

// ---------------- atomic-free CSR scatter, 4-edge ILP ----------------
__global__ __launch_bounds__(256) void scatter_kernel(
        const int* __restrict__ src, const int* __restrict__ dst,
        const int* __restrict__ rnk, const int* __restrict__ row_ptr,
        int* __restrict__ srcs, int E) {
    int base = blockIdx.x * 1024 + threadIdx.x;
    int s[4], d[4], r[4], rp[4];
    #pragma unroll
    for (int k = 0; k < 4; k++) {
        int e = base + k * 256;
        if (e < E) { d[k] = dst[e]; r[k] = rnk[e]; s[k] = src[e]; }
    }
    #pragma unroll
    for (int k = 0; k < 4; k++) {
        int e = base + k * 256;
        if (e < E) rp[k] = row_ptr[d[k]];
    }
    #pragma unroll
    for (int k = 0; k < 4; k++) {
        int e = base + k * 256;
        if (e < E) srcs[rp[k] + r[k]] = s[k];
    }
}

// ---------------- weight prep: W[k][n] -> WT[n][k] hi/lo bf16 (4 layers) ----------------
__global__ __launch_bounds__(256) void wprep_kernel(
        const float* __restrict__ W1, const float* __restrict__ W2,
        const float* __restrict__ W3, const float* __restrict__ W4,
        ushort* __restrict__ WTh, ushort* __restrict__ WTl) {
    int i = blockIdx.x * blockDim.x + threadIdx.x;   // 4*16384
    int l = i >> 14, r = i & 16383;
    int k = r >> 7, nn = r & 127;
    const float* W = (l == 0) ? W1 : (l == 1) ? W2 : (l == 2) ? W3 : W4;
    float w = W[k * HN + nn];
    uint hi = bf16rne(w);
    float fhi = __uint_as_float(hi << 16);
    uint lo = bf16rne(w - fhi);
    WTh[(size_t)l * 16384 + nn * HN + k] = (ushort)hi;
    WTl[(size_t)l * 16384 + nn * HN + k] = (ushort)lo;
}

// ---------------- pack: fp32 * onorm -> halved bf16 [2][N][64]bf16 ----------------
__global__ __launch_bounds__(256) void pack_kernel(
        const float* __restrict__ in, const float* __restrict__ onorm,
        ushort* __restrict__ out, int nrows) {
    int i = blockIdx.x * blockDim.x + threadIdx.x;
    if (i >= nrows * 32) return;
    int row = i >> 5, q4 = i & 31;
    float w = onorm[row];
    float4 v = ((const float4*)in)[i];
    ushort4 o = make_ushort4((ushort)bf16rne(v.x * w), (ushort)bf16rne(v.y * w),
                             (ushort)bf16rne(v.z * w), (ushort)bf16rne(v.w * w));
    int h = q4 >> 4, lc = (q4 * 2) & 31;   // half, uint offset within half-row
    *(ushort4*)(out + (((size_t)h * nrows + row) * 32 + lc) * 2) = o;
}

// ---------------- fused BN-apply + lrelu + onorm-fold + halved bf16 pack ----------------
__global__ __launch_bounds__(256) void bnpack_kernel(
        const float* __restrict__ in, ushort* __restrict__ out,
        const float* __restrict__ scale, const float* __restrict__ shift,
        const float* __restrict__ onorm, int nrows) {
    int i = blockIdx.x * blockDim.x + threadIdx.x;
    if (i >= nrows * 32) return;
    int row = i >> 5, q4 = i & 31;
    int cp = q4 << 2;
    float w = onorm[row];
    float4 v = ((const float4*)in)[i];
    float4 s = *(const float4*)(scale + cp);
    float4 t = *(const float4*)(shift + cp);
    float h0 = fmaf(v.x, s.x, t.x); h0 = (h0 >= 0.f) ? h0 : SLOPEV * h0;
    float h1 = fmaf(v.y, s.y, t.y); h1 = (h1 >= 0.f) ? h1 : SLOPEV * h1;
    float h2 = fmaf(v.z, s.z, t.z); h2 = (h2 >= 0.f) ? h2 : SLOPEV * h2;
    float h3 = fmaf(v.w, s.w, t.w); h3 = (h3 >= 0.f) ? h3 : SLOPEV * h3;
    ushort4 o = make_ushort4((ushort)bf16rne(h0 * w), (ushort)bf16rne(h1 * w),
                             (ushort)bf16rne(h2 * w), (ushort)bf16rne(h3 * w));
    int h = q4 >> 4, lc = (q4 * 2) & 31;
    *(ushort4*)(out + (((size_t)h * nrows + row) * 32 + lc) * 2) = o;
}

// ---------------- halved aggregation: 2 passes, 128 B (1 line) per gather ----------------
// grid = nodeBlocks*2; half = blockIdx/nodeBlocks (temporal separation -> per-pass
// working set 12.8 MB, better per-XCD L2 residency; locality heuristic only).
// Wave = 1 node; two 32-lane groups process interleaved edges of the same half.
__global__ __launch_bounds__(256) void agg_kernel(
        const uint* __restrict__ xb, uint* __restrict__ outb,
        const int* __restrict__ srcs, const int* __restrict__ row_ptr,
        const float* __restrict__ inorm, int n, int nodeBlocks) {
    int h = blockIdx.x / nodeBlocks;
    int nb = blockIdx.x - h * nodeBlocks;
    int node = nb * 4 + (threadIdx.x >> 6);
    if (node >= n) return;
    int lane = threadIdx.x & 63;
    int g = lane >> 5, li = lane & 31;
    const uint* Q = xb + (size_t)h * n * 32;
    int rp0 = row_ptr[node], rp1 = row_ptr[node + 1];
    float accx = 0.f, accy = 0.f;
    int j = rp0 + g;
    for (; j + 6 < rp1; j += 8) {
        int s0 = srcs[j], s1 = srcs[j + 2], s2 = srcs[j + 4], s3 = srcs[j + 6];
        uint u0 = Q[(size_t)s0 * 32 + li];
        uint u1 = Q[(size_t)s1 * 32 + li];
        uint u2 = Q[(size_t)s2 * 32 + li];
        uint u3 = Q[(size_t)s3 * 32 + li];
        accx += __uint_as_float(u0 << 16) + __uint_as_float(u1 << 16)
              + __uint_as_float(u2 << 16) + __uint_as_float(u3 << 16);
        accy += __uint_as_float(u0 & 0xffff0000u) + __uint_as_float(u1 & 0xffff0000u)
              + __uint_as_float(u2 & 0xffff0000u) + __uint_as_float(u3 & 0xffff0000u);
    }
    for (; j < rp1; j += 2) {
        uint u0 = Q[(size_t)srcs[j] * 32 + li];
        accx += __uint_as_float(u0 << 16);
        accy += __uint_as_float(u0 & 0xffff0000u);
    }
    accx += __shfl_xor(accx, 32); accy += __shfl_xor(accy, 32);
    if (g == 0) {
        float wi = inorm[node];
        uint o = bf16rne(accx * wi) | (bf16rne(accy * wi) << 16);
        outb[((size_t)h * n + node) * 32 + li] = o;
    }
}

// ---------------- MFMA GEMM, 512 threads / 128 rows per block, halved A ----------------
template<int DO_STATS, int DO_LRELU, int DO_PACK, int DO_CLS>
__global__ __launch_bounds__(512) void gemm_mfma(
        const ushort* __restrict__ A, const uint4* __restrict__ WTh4,
        const uint4* __restrict__ WTl4, const float* __restrict__ bias,
        void* __restrict__ outv, float* __restrict__ colsum, float* __restrict__ colsq,
        const float* __restrict__ onorm,
        const float* __restrict__ Wc, const float* __restrict__ bc, int n) {
    __shared__ uint4 sW[4096];   // hi | lo — 64 KB
    int tid = threadIdx.x;
    #pragma unroll
    for (int it = 0; it < 4; it++) {
        int j = it * 512 + tid;
        int nrow = j >> 4, c = j & 15;
        int sidx = nrow * 16 + (c ^ (nrow & 15));
        sW[sidx] = WTh4[j];
        sW[2048 + sidx] = WTl4[j];
    }
    __syncthreads();

    int wave = tid >> 6, lane = tid & 63;
    int l15 = lane & 15, quad = lane >> 4;
    int rbase = blockIdx.x * 128 + wave * 16;
    int arow = rbase + l15; if (arow > n - 1) arow = n - 1;

    bf16x8 af[4];
    #pragma unroll
    for (int kc = 0; kc < 4; kc++) {   // bf16 cols kc*32+quad*8: half = c0>>6
        int c0 = kc * 32 + quad * 8;
        af[kc] = *(const bf16x8*)(A + ((size_t)(c0 >> 6) * n + arow) * 64 + (c0 & 63));
    }

    f32x4 acc[8];
    #pragma unroll
    for (int t = 0; t < 8; t++) acc[t] = (f32x4){0.f, 0.f, 0.f, 0.f};

    #pragma unroll
    for (int t = 0; t < 8; t++) {
        int nn = t * 16 + l15;
        int base = nn * 16, sw = nn & 15;
        #pragma unroll
        for (int kc = 0; kc < 4; kc++) {
            int c = kc * 4 + quad;
            bf16x8 bh = *(const bf16x8*)&sW[base + (c ^ sw)];
            acc[t] = __builtin_amdgcn_mfma_f32_16x16x32_bf16(af[kc], bh, acc[t], 0, 0, 0);
        }
        #pragma unroll
        for (int kc = 0; kc < 4; kc++) {
            int c = kc * 4 + quad;
            bf16x8 bl = *(const bf16x8*)&sW[2048 + base + (c ^ sw)];
            acc[t] = __builtin_amdgcn_mfma_f32_16x16x32_bf16(af[kc], bl, acc[t], 0, 0, 0);
        }
    }

    if (DO_CLS) {
        float bvt[8];
        #pragma unroll
        for (int t = 0; t < 8; t++) bvt[t] = bias[t * 16 + l15];
        #pragma unroll
        for (int c = 0; c < NC; c++) {
            float cl[4] = {0.f, 0.f, 0.f, 0.f};
            #pragma unroll
            for (int t = 0; t < 8; t++) {
                float wcv = Wc[(t * 16 + l15) * NC + c];
                #pragma unroll
                for (int i = 0; i < 4; i++) {
                    float v = acc[t][i] + bvt[t];
                    v = (v >= 0.f) ? v : SLOPEV * v;
                    cl[i] = fmaf(v, wcv, cl[i]);
                }
            }
            #pragma unroll
            for (int i = 0; i < 4; i++) {
                cl[i] += __shfl_xor(cl[i], 1);
                cl[i] += __shfl_xor(cl[i], 2);
                cl[i] += __shfl_xor(cl[i], 4);
                cl[i] += __shfl_xor(cl[i], 8);
            }
            if (l15 == 0) {
                float bcv = bc[c];
                #pragma unroll
                for (int i = 0; i < 4; i++) {
                    int row = rbase + quad * 4 + i;
                    if (row < n) ((float*)outv)[(size_t)row * NC + c] = cl[i] + bcv;
                }
            }
        }
        return;
    }

    float sarr[8], qarr[8];
    #pragma unroll
    for (int t = 0; t < 8; t++) {
        int col = t * 16 + l15;
        float bv = bias[col];
        float s = 0.f, q = 0.f;
        #pragma unroll
        for (int i = 0; i < 4; i++) {
            int row = rbase + quad * 4 + i;
            float v = acc[t][i] + bv;
            if (DO_LRELU) v = (v >= 0.f) ? v : SLOPEV * v;
            if (row < n) {
                if (DO_PACK) {
                    ((ushort*)outv)[((size_t)(col >> 6) * n + row) * 64 + (col & 63)] =
                        (ushort)bf16rne(v * onorm[row]);
                } else {
                    ((float*)outv)[(size_t)row * HN + col] = v;
                }
                if (DO_STATS) { s += v; q += v * v; }
            }
        }
        if (DO_STATS) {
            s += __shfl_xor(s, 16); q += __shfl_xor(q, 16);
            s += __shfl_xor(s, 32); q += __shfl_xor(q, 32);
        }
        sarr[t] = s; qarr[t] = q;
    }

    if (DO_STATS) {
        __syncthreads();
        float* sSum = (float*)sW;
        float* sSq  = (float*)sW + 1024;
        if (quad == 0) {
            #pragma unroll
            for (int t = 0; t < 8; t++) {
                sSum[wave * 128 + t * 16 + l15] = sarr[t];
                sSq [wave * 128 + t * 16 + l15] = qarr[t];
            }
        }
        __syncthreads();
        if (tid < 128) {
            float s = 0.f, q = 0.f;
            #pragma unroll
            for (int w = 0; w < 8; w++) { s += sSum[w * 128 + tid]; q += sSq[w * 128 + tid]; }
            atomicAdd(&colsum[tid], s);
            atomicAdd(&colsq[tid], q);
        }
    }
}

// ---------------- BN finalize ----------------
__global__ void bn_finalize(const float* __restrict__ colsum, const float* __restrict__ colsq,
                            const float* __restrict__ gamma, const float* __restrict__ beta,
                            float* __restrict__ scale, float* __restrict__ shift, int n) {
    int c = threadIdx.x;
    if (c < HN) {
        float inv = 1.f / (float)n;
        float mean = colsum[c] * inv;
        float var = colsq[c] * inv - mean * mean;
        if (var < 0.f) var = 0.f;
        float s = gamma[c] * rsqrtf(var + EPSV);
        scale[c] = s;
        shift[c] = beta[c] - mean * s;
    }
}

extern "C" void kernel_launch(void* const* d_in, const int* in_sizes, int n_in,
                              void* d_out, int out_size, void* d_ws, size_t ws_size,
                              hipStream_t stream) {
    const float* node_feat = (const float*)d_in[0];
    const int*   src    = (const int*)d_in[1];
    const int*   dst    = (const int*)d_in[2];
    const float* W1     = (const float*)d_in[3];
    const float* b1     = (const float*)d_in[4];
    const float* W2     = (const float*)d_in[5];
    const float* b2     = (const float*)d_in[6];
    const float* gamma1 = (const float*)d_in[7];
    const float* beta1  = (const float*)d_in[8];
    const float* gamma2 = (const float*)d_in[9];
    const float* beta2  = (const float*)d_in[10];
    const float* Wn1    = (const float*)d_in[11];
    const float* bn1    = (const float*)d_in[12];
    const float* Wn2    = (const float*)d_in[13];
    const float* bn2    = (const float*)d_in[14];
    const float* Wc     = (const float*)d_in[15];
    const float* bc     = (const float*)d_in[16];
    float* out = (float*)d_out;

    const int N = in_sizes[0] / HN;
    const int E = in_sizes[1];

    char* p = (char*)d_ws;
    float* bufA  = (float*)p; p += (size_t)N * HN * 4;   // lo: HbA(bf16 halved), hi: Abf
    float* bufB  = (float*)p; p += (size_t)N * HN * 4;   // fp32 gemm out / HbB(bf16 halved)
    float* onorm = (float*)p; p += (size_t)N * 4;
    float* inorm = (float*)p; p += (size_t)N * 4;
    float* scale = (float*)p; p += HN * 4;
    float* shift = (float*)p; p += HN * 4;
    char* zbase = p;
    float* cs1 = (float*)p; p += HN * 4;
    float* cq1 = (float*)p; p += HN * 4;
    float* cs2 = (float*)p; p += HN * 4;
    float* cq2 = (float*)p; p += HN * 4;
    int* cntI  = (int*)p; p += (size_t)N * 4;
    int* degO8 = (int*)p; p += (size_t)8 * N * 4;        // per-XCD slices
    size_t zbytes = (size_t)(p - zbase);
    int* row_ptr = (int*)p; p += (size_t)(N + 4) * 4;
    int* blockSums = (int*)p; p += 1024 * 4;
    int* rnk     = (int*)p; p += (size_t)E * 4;
    int* srcs    = (int*)p; p += (size_t)E * 4;
    ushort* WTh  = (ushort*)p; p += 4 * 16384 * 2;
    ushort* WTl  = (ushort*)p; p += 4 * 16384 * 2;
    if ((size_t)(p - (char*)d_ws) > ws_size) return;

    hipMemsetAsync(zbase, 0, zbytes, stream);

    int gE4 = (E + 1023) / 1024;
    int nb = (N + 1023) / 1024;
    rank_kernel<<<gE4, 256, 0, stream>>>(src, dst, degO8, cntI, rnk, E, N);
    scan_partial<<<nb, 256, 0, stream>>>(cntI, blockSums, N);
    scan_blocksums<<<1, 1024, 0, stream>>>(blockSums, nb);
    scan_final<<<nb, 256, 0, stream>>>(cntI, degO8, blockSums, row_ptr, onorm, inorm, N, E);
    scatter_kernel<<<gE4, 256, 0, stream>>>(src, dst, rnk, row_ptr, srcs, E);
    wprep_kernel<<<256, 256, 0, stream>>>(W1, W2, Wn1, Wn2, WTh, WTl);

    int nodeBlocks = (N + 3) / 4;
    int gAgg = nodeBlocks * 2;          // two half-passes
    int gGemm = (N + 127) / 128;
    int gApply = (N * 32 + 255) / 256;

    ushort* HbA = (ushort*)bufA;
    ushort* Abf = (ushort*)bufA + (size_t)N * HN;
    ushort* HbB = (ushort*)bufB;

    // L1
    pack_kernel<<<gApply, 256, 0, stream>>>(node_feat, onorm, HbA, N);
    agg_kernel<<<gAgg, 256, 0, stream>>>((const uint*)HbA, (uint*)Abf, srcs, row_ptr, inorm, N, nodeBlocks);
    gemm_mfma<1, 0, 0, 0><<<gGemm, 512, 0, stream>>>(Abf, (const uint4*)WTh, (const uint4*)WTl,
                                                     b1, bufB, cs1, cq1, nullptr, nullptr, nullptr, N);
    bn_finalize<<<1, 128, 0, stream>>>(cs1, cq1, gamma1, beta1, scale, shift, N);
    bnpack_kernel<<<gApply, 256, 0, stream>>>(bufB, HbA, scale, shift, onorm, N);

    // L2
    agg_kernel<<<gAgg, 256, 0, stream>>>((const uint*)HbA, (uint*)Abf, srcs, row_ptr, inorm, N, nodeBlocks);
    gemm_mfma<1, 0, 0, 0><<<gGemm, 512, 0, stream>>>(Abf, (const uint4*)(WTh + 16384),
                                                     (const uint4*)(WTl + 16384),
                                                     b2, bufB, cs2, cq2, nullptr, nullptr, nullptr, N);
    bn_finalize<<<1, 128, 0, stream>>>(cs2, cq2, gamma2, beta2, scale, shift, N);
    bnpack_kernel<<<gApply, 256, 0, stream>>>(bufB, HbA, scale, shift, onorm, N);

    // L3: gemm packs bf16*onorm (halved layout)
    agg_kernel<<<gAgg, 256, 0, stream>>>((const uint*)HbA, (uint*)Abf, srcs, row_ptr, inorm, N, nodeBlocks);
    gemm_mfma<0, 1, 1, 0><<<gGemm, 512, 0, stream>>>(Abf, (const uint4*)(WTh + 2 * 16384),
                                                     (const uint4*)(WTl + 2 * 16384),
                                                     bn1, HbB, nullptr, nullptr, onorm, nullptr, nullptr, N);

    // L4: gemm + fused lrelu + classifier -> d_out
    agg_kernel<<<gAgg, 256, 0, stream>>>((const uint*)HbB, (uint*)Abf, srcs, row_ptr, inorm, N, nodeBlocks);
    gemm_mfma<0, 0, 0, 1><<<gGemm, 512, 0, stream>>>(Abf, (const uint4*)(WTh + 3 * 16384),
                                                     (const uint4*)(WTl + 3 * 16384),
                                                     bn2, out, nullptr, nullptr, nullptr, Wc, bc, N);
}

// Round 10
// 801.634 us; speedup vs baseline: 1.1423x; 1.1423x over previous
//
#include <hip/hip_runtime.h>
#include <math.h>

#define HN 128
#define NC 8
#define EPSV 1e-5f
#define SLOPEV 0.01f

typedef __attribute__((ext_vector_type(4))) float f32x4;
typedef __attribute__((ext_vector_type(8))) short bf16x8;

__device__ __forceinline__ uint bf16rne(float f) {
    uint u = __float_as_uint(f);
    return (u + 0x7fffu + ((u >> 16) & 1u)) >> 16;
}

__device__ __forceinline__ int xcc_id() {
    int x;
    asm volatile("s_getreg_b32 %0, hwreg(HW_REG_XCC_ID)" : "=s"(x));
    return x & 7;
}

// ---------------- rank: per-XCD degO + per-XCD in-count rank (local-L2 atomics) ----------------
// rnk[e] = (xcc << 28) | local_rank.  Global slot resolved in scatter via xcdoff8.
__global__ __launch_bounds__(256) void rank_kernel(
        const int* __restrict__ src, const int* __restrict__ dst,
        int* __restrict__ degO8, int* __restrict__ cntI8,
        int* __restrict__ rnk, int E, int n) {
    int x = xcc_id();
    int* myDeg = degO8 + (size_t)x * n;
    int* myCnt = cntI8 + (size_t)x * n;
    int base = blockIdx.x * 1024 + threadIdx.x;
    int s[4], d[4], r[4];
    #pragma unroll
    for (int k = 0; k < 4; k++) {
        int e = base + k * 256;
        if (e < E) { s[k] = src[e]; d[k] = dst[e]; }
    }
    #pragma unroll
    for (int k = 0; k < 4; k++) {
        int e = base + k * 256;
        if (e < E)
            __hip_atomic_fetch_add(&myDeg[s[k]], 1, __ATOMIC_RELAXED,
                                   __HIP_MEMORY_SCOPE_WORKGROUP);
    }
    #pragma unroll
    for (int k = 0; k < 4; k++) {
        int e = base + k * 256;
        if (e < E)
            r[k] = __hip_atomic_fetch_add(&myCnt[d[k]], 1, __ATOMIC_RELAXED,
                                          __HIP_MEMORY_SCOPE_WORKGROUP);
    }
    #pragma unroll
    for (int k = 0; k < 4; k++) {
        int e = base + k * 256;
        if (e < E) rnk[e] = (x << 28) | r[k];
    }
}

// ---------------- hierarchical exclusive scan over deg = sum_x cntI8[x][i] ----------------
__global__ __launch_bounds__(256) void scan_partial(const int* __restrict__ cntI8,
                                                    int* __restrict__ blockSums, int n) {
    __shared__ int sS[256];
    int tid = threadIdx.x;
    int base = blockIdx.x * 1024 + tid * 4;
    int s = 0;
    #pragma unroll
    for (int j = 0; j < 4; j++) {
        int idx = base + j;
        if (idx < n) {
            #pragma unroll
            for (int x = 0; x < 8; x++) s += cntI8[(size_t)x * n + idx];
        }
    }
    sS[tid] = s;
    __syncthreads();
    for (int off = 128; off; off >>= 1) {
        if (tid < off) sS[tid] += sS[tid + off];
        __syncthreads();
    }
    if (tid == 0) blockSums[blockIdx.x] = sS[0];
}

__global__ __launch_bounds__(1024) void scan_blocksums(int* __restrict__ blockSums, int nb) {
    __shared__ int sS[1024];
    int tid = threadIdx.x;
    int v = (tid < nb) ? blockSums[tid] : 0;
    sS[tid] = v;
    __syncthreads();
    for (int off = 1; off < 1024; off <<= 1) {
        int t = (tid >= off) ? sS[tid - off] : 0;
        __syncthreads();
        sS[tid] += t;
        __syncthreads();
    }
    if (tid < nb) blockSums[tid] = sS[tid] - v;
}

// local scan + block offset -> row_ptr; per-XCD prefix -> xcdoff8; norms
__global__ __launch_bounds__(256) void scan_final(const int* __restrict__ cntI8,
                                                  const int* __restrict__ degO8,
                                                  const int* __restrict__ blockSums,
                                                  int* __restrict__ row_ptr,
                                                  int* __restrict__ xcdoff8,
                                                  float* __restrict__ onorm,
                                                  float* __restrict__ inorm, int n, int E) {
    __shared__ int sS[256];
    int tid = threadIdx.x;
    int base = blockIdx.x * 1024 + tid * 4;
    int v[4];
    int tot = 0;
    #pragma unroll
    for (int j = 0; j < 4; j++) {
        int idx = base + j;
        int deg = 0;
        if (idx < n) {
            #pragma unroll
            for (int x = 0; x < 8; x++) {
                xcdoff8[(size_t)x * n + idx] = deg;      // exclusive prefix over XCDs
                deg += cntI8[(size_t)x * n + idx];
            }
        }
        v[j] = tot;
        tot += deg;
    }
    sS[tid] = tot;
    __syncthreads();
    for (int off = 1; off < 256; off <<= 1) {
        int t = (tid >= off) ? sS[tid - off] : 0;
        __syncthreads();
        sS[tid] += t;
        __syncthreads();
    }
    int tb = blockSums[blockIdx.x] + sS[tid] - tot;
    int run = 0;
    #pragma unroll
    for (int j = 0; j < 4; j++) {
        int idx = base + j;
        if (idx < n) {
            row_ptr[idx] = tb + run;
            int deg = 0, dO = 0;
            #pragma unroll
            for (int x = 0; x < 8; x++) {
                deg += cntI8[(size_t)x * n + idx];
                dO  += degO8[(size_t)x * n + idx];
            }
            run += deg;
            float a = (float)dO; if (a < 1.f) a = 1.f;
            float b = (float)deg; if (b < 1.f) b = 1.f;
            onorm[idx] = rsqrtf(a);
            inorm[idx] = rsqrtf(b);
        }
    }
    if (blockIdx.x == 0 && tid == 0) row_ptr[n] = E;
}

// ---------------- atomic-free CSR scatter: slot = row_ptr + xcdoff + local rank ----------------
__global__ __launch_bounds__(256) void scatter_kernel(
        const int* __restrict__ src, const int* __restrict__ dst,
        const int* __restrict__ rnk, const int* __restrict__ row_ptr,
        const int* __restrict__ xcdoff8, int* __restrict__ srcs, int E, int n) {
    int base = blockIdx.x * 1024 + threadIdx.x;
    int s[4], d[4], r[4], rp[4], xo[4];
    #pragma unroll
    for (int k = 0; k < 4; k++) {
        int e = base + k * 256;
        if (e < E) { d[k] = dst[e]; r[k] = rnk[e]; s[k] = src[e]; }
    }
    #pragma unroll
    for (int k = 0; k < 4; k++) {
        int e = base + k * 256;
        if (e < E) {
            rp[k] = row_ptr[d[k]];
            xo[k] = xcdoff8[(size_t)(r[k] >> 28) * n + d[k]];
        }
    }
    #pragma unroll
    for (int k = 0; k < 4; k++) {
        int e = base + k * 256;
        if (e < E) srcs[rp[k] + xo[k] + (r[k] & 0x0FFFFFFF)] = s[k];
    }
}

// ---------------- weight prep: W[k][n] -> WT[n][k] hi/lo bf16 (4 layers) ----------------
__global__ __launch_bounds__(256) void wprep_kernel(
        const float* __restrict__ W1, const float* __restrict__ W2,
        const float* __restrict__ W3, const float* __restrict__ W4,
        ushort* __restrict__ WTh, ushort* __restrict__ WTl) {
    int i = blockIdx.x * blockDim.x + threadIdx.x;   // 4*16384
    int l = i >> 14, r = i & 16383;
    int k = r >> 7, nn = r & 127;
    const float* W = (l == 0) ? W1 : (l == 1) ? W2 : (l == 2) ? W3 : W4;
    float w = W[k * HN + nn];
    uint hi = bf16rne(w);
    float fhi = __uint_as_float(hi << 16);
    uint lo = bf16rne(w - fhi);
    WTh[(size_t)l * 16384 + nn * HN + k] = (ushort)hi;
    WTl[(size_t)l * 16384 + nn * HN + k] = (ushort)lo;
}

// ---------------- pack: fp32 * onorm -> bf16 contiguous rows ----------------
__global__ __launch_bounds__(256) void pack_kernel(
        const float* __restrict__ in, const float* __restrict__ onorm,
        ushort* __restrict__ out, int total4) {
    int i = blockIdx.x * blockDim.x + threadIdx.x;
    if (i >= total4) return;
    float w = onorm[i >> 5];
    float4 v = ((const float4*)in)[i];
    ushort4 o = make_ushort4((ushort)bf16rne(v.x * w), (ushort)bf16rne(v.y * w),
                             (ushort)bf16rne(v.z * w), (ushort)bf16rne(v.w * w));
    *(ushort4*)(out + (size_t)i * 4) = o;
}

// ---------------- fused BN-apply + lrelu + onorm-fold + bf16 pack ----------------
__global__ __launch_bounds__(256) void bnpack_kernel(
        const float* __restrict__ in, ushort* __restrict__ out,
        const float* __restrict__ scale, const float* __restrict__ shift,
        const float* __restrict__ onorm, int total4) {
    int i = blockIdx.x * blockDim.x + threadIdx.x;
    if (i >= total4) return;
    int cp = (i & 31) << 2;
    float w = onorm[i >> 5];
    float4 v = ((const float4*)in)[i];
    float4 s = *(const float4*)(scale + cp);
    float4 t = *(const float4*)(shift + cp);
    float h0 = fmaf(v.x, s.x, t.x); h0 = (h0 >= 0.f) ? h0 : SLOPEV * h0;
    float h1 = fmaf(v.y, s.y, t.y); h1 = (h1 >= 0.f) ? h1 : SLOPEV * h1;
    float h2 = fmaf(v.z, s.z, t.z); h2 = (h2 >= 0.f) ? h2 : SLOPEV * h2;
    float h3 = fmaf(v.w, s.w, t.w); h3 = (h3 >= 0.f) ? h3 : SLOPEV * h3;
    ushort4 o = make_ushort4((ushort)bf16rne(h0 * w), (ushort)bf16rne(h1 * w),
                             (ushort)bf16rne(h2 * w), (ushort)bf16rne(h3 * w));
    *(ushort4*)(out + (size_t)i * 4) = o;
}

// ---------------- aggregation: one wave per dst node, 256 B contiguous rows ----------------
__global__ __launch_bounds__(256) void agg_kernel(
        const uint* __restrict__ xb, uint* __restrict__ out,
        const int* __restrict__ srcs, const int* __restrict__ row_ptr,
        const float* __restrict__ inorm, int n) {
    int node = blockIdx.x * 4 + (threadIdx.x >> 6);
    if (node >= n) return;
    int lane = threadIdx.x & 63;
    int rp0 = row_ptr[node], rp1 = row_ptr[node + 1];
    float accx = 0.f, accy = 0.f;
    int j = rp0;
    for (; j + 3 < rp1; j += 4) {
        int s0 = srcs[j], s1 = srcs[j + 1], s2 = srcs[j + 2], s3 = srcs[j + 3];
        uint u0 = xb[(size_t)s0 * 64 + lane];
        uint u1 = xb[(size_t)s1 * 64 + lane];
        uint u2 = xb[(size_t)s2 * 64 + lane];
        uint u3 = xb[(size_t)s3 * 64 + lane];
        accx += __uint_as_float(u0 << 16) + __uint_as_float(u1 << 16)
              + __uint_as_float(u2 << 16) + __uint_as_float(u3 << 16);
        accy += __uint_as_float(u0 & 0xffff0000u) + __uint_as_float(u1 & 0xffff0000u)
              + __uint_as_float(u2 & 0xffff0000u) + __uint_as_float(u3 & 0xffff0000u);
    }
    for (; j < rp1; j++) {
        uint u0 = xb[(size_t)srcs[j] * 64 + lane];
        accx += __uint_as_float(u0 << 16);
        accy += __uint_as_float(u0 & 0xffff0000u);
    }
    float wi = inorm[node];
    uint o = bf16rne(accx * wi) | (bf16rne(accy * wi) << 16);
    out[(size_t)node * 64 + lane] = o;
}

// ---------------- MFMA GEMM, 512 threads / 128 rows per block ----------------
template<int DO_STATS, int DO_LRELU, int DO_PACK, int DO_CLS>
__global__ __launch_bounds__(512) void gemm_mfma(
        const ushort* __restrict__ A, const uint4* __restrict__ WTh4,
        const uint4* __restrict__ WTl4, const float* __restrict__ bias,
        void* __restrict__ outv, float* __restrict__ colsum, float* __restrict__ colsq,
        const float* __restrict__ onorm,
        const float* __restrict__ Wc, const float* __restrict__ bc, int n) {
    __shared__ uint4 sW[4096];   // hi | lo — 64 KB
    int tid = threadIdx.x;
    #pragma unroll
    for (int it = 0; it < 4; it++) {
        int j = it * 512 + tid;
        int nrow = j >> 4, c = j & 15;
        int sidx = nrow * 16 + (c ^ (nrow & 15));
        sW[sidx] = WTh4[j];
        sW[2048 + sidx] = WTl4[j];
    }
    __syncthreads();

    int wave = tid >> 6, lane = tid & 63;
    int l15 = lane & 15, quad = lane >> 4;
    int rbase = blockIdx.x * 128 + wave * 16;
    int arow = rbase + l15; if (arow > n - 1) arow = n - 1;

    bf16x8 af[4];
    #pragma unroll
    for (int kc = 0; kc < 4; kc++)
        af[kc] = *(const bf16x8*)(A + (size_t)arow * HN + kc * 32 + quad * 8);

    f32x4 acc[8];
    #pragma unroll
    for (int t = 0; t < 8; t++) acc[t] = (f32x4){0.f, 0.f, 0.f, 0.f};

    #pragma unroll
    for (int t = 0; t < 8; t++) {
        int nn = t * 16 + l15;
        int base = nn * 16, sw = nn & 15;
        #pragma unroll
        for (int kc = 0; kc < 4; kc++) {
            int c = kc * 4 + quad;
            bf16x8 bh = *(const bf16x8*)&sW[base + (c ^ sw)];
            acc[t] = __builtin_amdgcn_mfma_f32_16x16x32_bf16(af[kc], bh, acc[t], 0, 0, 0);
        }
        #pragma unroll
        for (int kc = 0; kc < 4; kc++) {
            int c = kc * 4 + quad;
            bf16x8 bl = *(const bf16x8*)&sW[2048 + base + (c ^ sw)];
            acc[t] = __builtin_amdgcn_mfma_f32_16x16x32_bf16(af[kc], bl, acc[t], 0, 0, 0);
        }
    }

    if (DO_CLS) {
        float bvt[8];
        #pragma unroll
        for (int t = 0; t < 8; t++) bvt[t] = bias[t * 16 + l15];
        #pragma unroll
        for (int c = 0; c < NC; c++) {
            float cl[4] = {0.f, 0.f, 0.f, 0.f};
            #pragma unroll
            for (int t = 0; t < 8; t++) {
                float wcv = Wc[(t * 16 + l15) * NC + c];
                #pragma unroll
                for (int i = 0; i < 4; i++) {
                    float v = acc[t][i] + bvt[t];
                    v = (v >= 0.f) ? v : SLOPEV * v;
                    cl[i] = fmaf(v, wcv, cl[i]);
                }
            }
            #pragma unroll
            for (int i = 0; i < 4; i++) {
                cl[i] += __shfl_xor(cl[i], 1);
                cl[i] += __shfl_xor(cl[i], 2);
                cl[i] += __shfl_xor(cl[i], 4);
                cl[i] += __shfl_xor(cl[i], 8);
            }
            if (l15 == 0) {
                float bcv = bc[c];
                #pragma unroll
                for (int i = 0; i < 4; i++) {
                    int row = rbase + quad * 4 + i;
                    if (row < n) ((float*)outv)[(size_t)row * NC + c] = cl[i] + bcv;
                }
            }
        }
        return;
    }

    float sarr[8], qarr[8];
    #pragma unroll
    for (int t = 0; t < 8; t++) {
        int col = t * 16 + l15;
        float bv = bias[col];
        float s = 0.f, q = 0.f;
        #pragma unroll
        for (int i = 0; i < 4; i++) {
            int row = rbase + quad * 4 + i;
            float v = acc[t][i] + bv;
            if (DO_LRELU) v = (v >= 0.f) ? v : SLOPEV * v;
            if (row < n) {
                if (DO_PACK) {
                    ((ushort*)outv)[(size_t)row * HN + col] = (ushort)bf16rne(v * onorm[row]);
                } else {
                    ((float*)outv)[(size_t)row * HN + col] = v;
                }
                if (DO_STATS) { s += v; q += v * v; }
            }
        }
        if (DO_STATS) {
            s += __shfl_xor(s, 16); q += __shfl_xor(q, 16);
            s += __shfl_xor(s, 32); q += __shfl_xor(q, 32);
        }
        sarr[t] = s; qarr[t] = q;
    }

    if (DO_STATS) {
        __syncthreads();
        float* sSum = (float*)sW;
        float* sSq  = (float*)sW + 1024;
        if (quad == 0) {
            #pragma unroll
            for (int t = 0; t < 8; t++) {
                sSum[wave * 128 + t * 16 + l15] = sarr[t];
                sSq [wave * 128 + t * 16 + l15] = qarr[t];
            }
        }
        __syncthreads();
        if (tid < 128) {
            float s = 0.f, q = 0.f;
            #pragma unroll
            for (int w = 0; w < 8; w++) { s += sSum[w * 128 + tid]; q += sSq[w * 128 + tid]; }
            atomicAdd(&colsum[tid], s);
            atomicAdd(&colsq[tid], q);
        }
    }
}

// ---------------- BN finalize ----------------
__global__ void bn_finalize(const float* __restrict__ colsum, const float* __restrict__ colsq,
                            const float* __restrict__ gamma, const float* __restrict__ beta,
                            float* __restrict__ scale, float* __restrict__ shift, int n) {
    int c = threadIdx.x;
    if (c < HN) {
        float inv = 1.f / (float)n;
        float mean = colsum[c] * inv;
        float var = colsq[c] * inv - mean * mean;
        if (var < 0.f) var = 0.f;
        float s = gamma[c] * rsqrtf(var + EPSV);
        scale[c] = s;
        shift[c] = beta[c] - mean * s;
    }
}

extern "C" void kernel_launch(void* const* d_in, const int* in_sizes, int n_in,
                              void* d_out, int out_size, void* d_ws, size_t ws_size,
                              hipStream_t stream) {
    const float* node_feat = (const float*)d_in[0];
    const int*   src    = (const int*)d_in[1];
    const int*   dst    = (const int*)d_in[2];
    const float* W1     = (const float*)d_in[3];
    const float* b1     = (const float*)d_in[4];
    const float* W2     = (const float*)d_in[5];
    const float* b2     = (const float*)d_in[6];
    const float* gamma1 = (const float*)d_in[7];
    const float* beta1  = (const float*)d_in[8];
    const float* gamma2 = (const float*)d_in[9];
    const float* beta2  = (const float*)d_in[10];
    const float* Wn1    = (const float*)d_in[11];
    const float* bn1    = (const float*)d_in[12];
    const float* Wn2    = (const float*)d_in[13];
    const float* bn2    = (const float*)d_in[14];
    const float* Wc     = (const float*)d_in[15];
    const float* bc     = (const float*)d_in[16];
    float* out = (float*)d_out;

    const int N = in_sizes[0] / HN;
    const int E = in_sizes[1];

    char* p = (char*)d_ws;
    float* bufA  = (float*)p; p += (size_t)N * HN * 4;   // lo: HbA(bf16), hi: Abf(bf16)
    float* bufB  = (float*)p; p += (size_t)N * HN * 4;   // fp32 gemm out / HbB(bf16)
    float* onorm = (float*)p; p += (size_t)N * 4;
    float* inorm = (float*)p; p += (size_t)N * 4;
    float* scale = (float*)p; p += HN * 4;
    float* shift = (float*)p; p += HN * 4;
    char* zbase = p;
    float* cs1 = (float*)p; p += HN * 4;
    float* cq1 = (float*)p; p += HN * 4;
    float* cs2 = (float*)p; p += HN * 4;
    float* cq2 = (float*)p; p += HN * 4;
    int* degO8 = (int*)p; p += (size_t)8 * N * 4;
    int* cntI8 = (int*)p; p += (size_t)8 * N * 4;
    size_t zbytes = (size_t)(p - zbase);
    int* xcdoff8 = (int*)p; p += (size_t)8 * N * 4;
    int* row_ptr = (int*)p; p += (size_t)(N + 4) * 4;
    int* blockSums = (int*)p; p += 1024 * 4;
    int* rnk     = (int*)p; p += (size_t)E * 4;
    int* srcs    = (int*)p; p += (size_t)E * 4;
    ushort* WTh  = (ushort*)p; p += 4 * 16384 * 2;
    ushort* WTl  = (ushort*)p; p += 4 * 16384 * 2;
    if ((size_t)(p - (char*)d_ws) > ws_size) return;

    hipMemsetAsync(zbase, 0, zbytes, stream);

    int gE4 = (E + 1023) / 1024;
    int nb = (N + 1023) / 1024;
    rank_kernel<<<gE4, 256, 0, stream>>>(src, dst, degO8, cntI8, rnk, E, N);
    scan_partial<<<nb, 256, 0, stream>>>(cntI8, blockSums, N);
    scan_blocksums<<<1, 1024, 0, stream>>>(blockSums, nb);
    scan_final<<<nb, 256, 0, stream>>>(cntI8, degO8, blockSums, row_ptr, xcdoff8,
                                       onorm, inorm, N, E);
    scatter_kernel<<<gE4, 256, 0, stream>>>(src, dst, rnk, row_ptr, xcdoff8, srcs, E, N);
    wprep_kernel<<<256, 256, 0, stream>>>(W1, W2, Wn1, Wn2, WTh, WTl);

    int gAgg = (N + 3) / 4;
    int gGemm = (N + 127) / 128;
    int gApply = (N * 32 + 255) / 256;

    ushort* HbA = (ushort*)bufA;
    ushort* Abf = (ushort*)bufA + (size_t)N * HN;
    ushort* HbB = (ushort*)bufB;

    // L1
    pack_kernel<<<gApply, 256, 0, stream>>>(node_feat, onorm, HbA, N * 32);
    agg_kernel<<<gAgg, 256, 0, stream>>>((const uint*)HbA, (uint*)Abf, srcs, row_ptr, inorm, N);
    gemm_mfma<1, 0, 0, 0><<<gGemm, 512, 0, stream>>>(Abf, (const uint4*)WTh, (const uint4*)WTl,
                                                     b1, bufB, cs1, cq1, nullptr, nullptr, nullptr, N);
    bn_finalize<<<1, 128, 0, stream>>>(cs1, cq1, gamma1, beta1, scale, shift, N);
    bnpack_kernel<<<gApply, 256, 0, stream>>>(bufB, HbA, scale, shift, onorm, N * 32);

    // L2
    agg_kernel<<<gAgg, 256, 0, stream>>>((const uint*)HbA, (uint*)Abf, srcs, row_ptr, inorm, N);
    gemm_mfma<1, 0, 0, 0><<<gGemm, 512, 0, stream>>>(Abf, (const uint4*)(WTh + 16384),
                                                     (const uint4*)(WTl + 16384),
                                                     b2, bufB, cs2, cq2, nullptr, nullptr, nullptr, N);
    bn_finalize<<<1, 128, 0, stream>>>(cs2, cq2, gamma2, beta2, scale, shift, N);
    bnpack_kernel<<<gApply, 256, 0, stream>>>(bufB, HbA, scale, shift, onorm, N * 32);

    // L3: gemm packs bf16*onorm directly
    agg_kernel<<<gAgg, 256, 0, stream>>>((const uint*)HbA, (uint*)Abf, srcs, row_ptr, inorm, N);
    gemm_mfma<0, 1, 1, 0><<<gGemm, 512, 0, stream>>>(Abf, (const uint4*)(WTh + 2 * 16384),
                                                     (const uint4*)(WTl + 2 * 16384),
                                                     bn1, HbB, nullptr, nullptr, onorm, nullptr, nullptr, N);

    // L4: gemm + fused lrelu + classifier -> d_out
    agg_kernel<<<gAgg, 256, 0, stream>>>((const uint*)HbB, (uint*)Abf, srcs, row_ptr, inorm, N);
    gemm_mfma<0, 0, 0, 1><<<gGemm, 512, 0, stream>>>(Abf, (const uint4*)(WTh + 3 * 16384),
                                                     (const uint4*)(WTl + 3 * 16384),
                                                     bn2, out, nullptr, nullptr, nullptr, Wc, bc, N);
}

// Round 11
// 743.475 us; speedup vs baseline: 1.2317x; 1.0782x over previous
//
#include <hip/hip_runtime.h>
#include <math.h>

#define HN 128
#define NC 8
#define EPSV 1e-5f
#define SLOPEV 0.01f

typedef __attribute__((ext_vector_type(4))) float f32x4;
typedef __attribute__((ext_vector_type(8))) short bf16x8;

__device__ __forceinline__ uint bf16rne(float f) {
    uint u = __float_as_uint(f);
    return (u + 0x7fffu + ((u >> 16) & 1u)) >> 16;
}

__device__ __forceinline__ float blo(uint u) { return __uint_as_float(u << 16); }
__device__ __forceinline__ float bhi(uint u) { return __uint_as_float(u & 0xffff0000u); }

__device__ __forceinline__ int xcc_id() {
    int x;
    asm volatile("s_getreg_b32 %0, hwreg(HW_REG_XCC_ID)" : "=s"(x));
    return x & 7;
}

// ---------------- rank: per-XCD degO (local slices) + device-scope in-count rank ----------------
__global__ __launch_bounds__(256) void rank_kernel(
        const int* __restrict__ src, const int* __restrict__ dst,
        int* __restrict__ degO8, int* __restrict__ cntI,
        int* __restrict__ rnk, int E, int n) {
    int* myDeg = degO8 + (size_t)xcc_id() * n;
    int base = blockIdx.x * 1024 + threadIdx.x;
    int s[4], d[4], r[4];
    #pragma unroll
    for (int k = 0; k < 4; k++) {
        int e = base + k * 256;
        if (e < E) { s[k] = src[e]; d[k] = dst[e]; }
    }
    #pragma unroll
    for (int k = 0; k < 4; k++) {
        int e = base + k * 256;
        if (e < E)
            __hip_atomic_fetch_add(&myDeg[s[k]], 1, __ATOMIC_RELAXED,
                                   __HIP_MEMORY_SCOPE_WORKGROUP);
    }
    #pragma unroll
    for (int k = 0; k < 4; k++) {
        int e = base + k * 256;
        if (e < E) r[k] = atomicAdd(&cntI[d[k]], 1);
    }
    #pragma unroll
    for (int k = 0; k < 4; k++) {
        int e = base + k * 256;
        if (e < E) rnk[e] = r[k];
    }
}

// ---------------- hierarchical exclusive scan ----------------
__global__ __launch_bounds__(256) void scan_partial(const int* __restrict__ degI,
                                                    int* __restrict__ blockSums, int n) {
    __shared__ int sS[256];
    int tid = threadIdx.x;
    int base = blockIdx.x * 1024 + tid * 4;
    int s = 0;
    #pragma unroll
    for (int j = 0; j < 4; j++) {
        int idx = base + j;
        s += (idx < n) ? degI[idx] : 0;
    }
    sS[tid] = s;
    __syncthreads();
    for (int off = 128; off; off >>= 1) {
        if (tid < off) sS[tid] += sS[tid + off];
        __syncthreads();
    }
    if (tid == 0) blockSums[blockIdx.x] = sS[0];
}

__global__ __launch_bounds__(1024) void scan_blocksums(int* __restrict__ blockSums, int nb) {
    __shared__ int sS[1024];
    int tid = threadIdx.x;
    int v = (tid < nb) ? blockSums[tid] : 0;
    sS[tid] = v;
    __syncthreads();
    for (int off = 1; off < 1024; off <<= 1) {
        int t = (tid >= off) ? sS[tid - off] : 0;
        __syncthreads();
        sS[tid] += t;
        __syncthreads();
    }
    if (tid < nb) blockSums[tid] = sS[tid] - v;
}

// local scan + block offset -> row_ptr; sums degO8 slices; computes norms
__global__ __launch_bounds__(256) void scan_final(const int* __restrict__ degI,
                                                  const int* __restrict__ degO8,
                                                  const int* __restrict__ blockSums,
                                                  int* __restrict__ row_ptr,
                                                  float* __restrict__ onorm,
                                                  float* __restrict__ inorm, int n, int E) {
    __shared__ int sS[256];
    int tid = threadIdx.x;
    int base = blockIdx.x * 1024 + tid * 4;
    int v[4];
    int tot = 0;
    #pragma unroll
    for (int j = 0; j < 4; j++) {
        int idx = base + j;
        int vv = (idx < n) ? degI[idx] : 0;
        v[j] = tot;
        tot += vv;
    }
    sS[tid] = tot;
    __syncthreads();
    for (int off = 1; off < 256; off <<= 1) {
        int t = (tid >= off) ? sS[tid - off] : 0;
        __syncthreads();
        sS[tid] += t;
        __syncthreads();
    }
    int tb = blockSums[blockIdx.x] + sS[tid] - tot;
    #pragma unroll
    for (int j = 0; j < 4; j++) {
        int idx = base + j;
        if (idx < n) {
            row_ptr[idx] = tb + v[j];
            int dsum = 0;
            #pragma unroll
            for (int s8 = 0; s8 < 8; s8++) dsum += degO8[(size_t)s8 * n + idx];
            float a = (float)dsum; if (a < 1.f) a = 1.f;
            float b = (float)degI[idx]; if (b < 1.f) b = 1.f;
            onorm[idx] = rsqrtf(a);
            inorm[idx] = rsqrtf(b);
        }
    }
    if (blockIdx.x == 0 && tid == 0) row_ptr[n] = E;
}

// ---------------- atomic-free CSR scatter, 4-edge ILP ----------------
__global__ __launch_bounds__(256) void scatter_kernel(
        const int* __restrict__ src, const int* __restrict__ dst,
        const int* __restrict__ rnk, const int* __restrict__ row_ptr,
        int* __restrict__ srcs, int E) {
    int base = blockIdx.x * 1024 + threadIdx.x;
    int s[4], d[4], r[4], rp[4];
    #pragma unroll
    for (int k = 0; k < 4; k++) {
        int e = base + k * 256;
        if (e < E) { d[k] = dst[e]; r[k] = rnk[e]; s[k] = src[e]; }
    }
    #pragma unroll
    for (int k = 0; k < 4; k++) {
        int e = base + k * 256;
        if (e < E) rp[k] = row_ptr[d[k]];
    }
    #pragma unroll
    for (int k = 0; k < 4; k++) {
        int e = base + k * 256;
        if (e < E) srcs[rp[k] + r[k]] = s[k];
    }
}

// ---------------- weight prep: W[k][n] -> WT[n][k] hi/lo bf16 (4 layers) ----------------
__global__ __launch_bounds__(256) void wprep_kernel(
        const float* __restrict__ W1, const float* __restrict__ W2,
        const float* __restrict__ W3, const float* __restrict__ W4,
        ushort* __restrict__ WTh, ushort* __restrict__ WTl) {
    int i = blockIdx.x * blockDim.x + threadIdx.x;   // 4*16384
    int l = i >> 14, r = i & 16383;
    int k = r >> 7, nn = r & 127;
    const float* W = (l == 0) ? W1 : (l == 1) ? W2 : (l == 2) ? W3 : W4;
    float w = W[k * HN + nn];
    uint hi = bf16rne(w);
    float fhi = __uint_as_float(hi << 16);
    uint lo = bf16rne(w - fhi);
    WTh[(size_t)l * 16384 + nn * HN + k] = (ushort)hi;
    WTl[(size_t)l * 16384 + nn * HN + k] = (ushort)lo;
}

// ---------------- pack: fp32 * onorm -> bf16 contiguous rows ----------------
__global__ __launch_bounds__(256) void pack_kernel(
        const float* __restrict__ in, const float* __restrict__ onorm,
        ushort* __restrict__ out, int total4) {
    int i = blockIdx.x * blockDim.x + threadIdx.x;
    if (i >= total4) return;
    float w = onorm[i >> 5];
    float4 v = ((const float4*)in)[i];
    ushort4 o = make_ushort4((ushort)bf16rne(v.x * w), (ushort)bf16rne(v.y * w),
                             (ushort)bf16rne(v.z * w), (ushort)bf16rne(v.w * w));
    *(ushort4*)(out + (size_t)i * 4) = o;
}

// ---------------- fused BN-apply + lrelu + onorm-fold + bf16 pack ----------------
__global__ __launch_bounds__(256) void bnpack_kernel(
        const float* __restrict__ in, ushort* __restrict__ out,
        const float* __restrict__ scale, const float* __restrict__ shift,
        const float* __restrict__ onorm, int total4) {
    int i = blockIdx.x * blockDim.x + threadIdx.x;
    if (i >= total4) return;
    int cp = (i & 31) << 2;
    float w = onorm[i >> 5];
    float4 v = ((const float4*)in)[i];
    float4 s = *(const float4*)(scale + cp);
    float4 t = *(const float4*)(shift + cp);
    float h0 = fmaf(v.x, s.x, t.x); h0 = (h0 >= 0.f) ? h0 : SLOPEV * h0;
    float h1 = fmaf(v.y, s.y, t.y); h1 = (h1 >= 0.f) ? h1 : SLOPEV * h1;
    float h2 = fmaf(v.z, s.z, t.z); h2 = (h2 >= 0.f) ? h2 : SLOPEV * h2;
    float h3 = fmaf(v.w, s.w, t.w); h3 = (h3 >= 0.f) ? h3 : SLOPEV * h3;
    ushort4 o = make_ushort4((ushort)bf16rne(h0 * w), (ushort)bf16rne(h1 * w),
                             (ushort)bf16rne(h2 * w), (ushort)bf16rne(h3 * w));
    *(ushort4*)(out + (size_t)i * 4) = o;
}

// ---------------- aggregation: wave per node, 2 lane-groups x uint2 (full 256 B rows) ----------------
// Group g (32 lanes, 8 B/lane = one contiguous row) handles edges j=rp0+g, rp0+g+2, ...
// 4-deep unroll -> 8 row-gathers in flight per wave. shfl_xor(32) merges groups.
__global__ __launch_bounds__(256) void agg_kernel(
        const uint2* __restrict__ xb2, uint2* __restrict__ out2,
        const int* __restrict__ srcs, const int* __restrict__ row_ptr,
        const float* __restrict__ inorm, int n) {
    int node = blockIdx.x * 4 + (threadIdx.x >> 6);
    if (node >= n) return;
    int lane = threadIdx.x & 63;
    int g = lane >> 5, li = lane & 31;
    int rp0 = row_ptr[node], rp1 = row_ptr[node + 1];
    float a0 = 0.f, a1 = 0.f, a2 = 0.f, a3 = 0.f;
    int j = rp0 + g;
    for (; j + 6 < rp1; j += 8) {
        int s0 = srcs[j], s1 = srcs[j + 2], s2 = srcs[j + 4], s3 = srcs[j + 6];
        uint2 u0 = xb2[(size_t)s0 * 32 + li];
        uint2 u1 = xb2[(size_t)s1 * 32 + li];
        uint2 u2 = xb2[(size_t)s2 * 32 + li];
        uint2 u3 = xb2[(size_t)s3 * 32 + li];
        a0 += blo(u0.x) + blo(u1.x) + blo(u2.x) + blo(u3.x);
        a1 += bhi(u0.x) + bhi(u1.x) + bhi(u2.x) + bhi(u3.x);
        a2 += blo(u0.y) + blo(u1.y) + blo(u2.y) + blo(u3.y);
        a3 += bhi(u0.y) + bhi(u1.y) + bhi(u2.y) + bhi(u3.y);
    }
    for (; j < rp1; j += 2) {
        uint2 u = xb2[(size_t)srcs[j] * 32 + li];
        a0 += blo(u.x); a1 += bhi(u.x);
        a2 += blo(u.y); a3 += bhi(u.y);
    }
    a0 += __shfl_xor(a0, 32); a1 += __shfl_xor(a1, 32);
    a2 += __shfl_xor(a2, 32); a3 += __shfl_xor(a3, 32);
    if (g == 0) {
        float wi = inorm[node];
        uint2 o;
        o.x = bf16rne(a0 * wi) | (bf16rne(a1 * wi) << 16);
        o.y = bf16rne(a2 * wi) | (bf16rne(a3 * wi) << 16);
        out2[(size_t)node * 32 + li] = o;
    }
}

// ---------------- MFMA GEMM, 512 threads / 128 rows per block ----------------
template<int DO_STATS, int DO_LRELU, int DO_PACK, int DO_CLS>
__global__ __launch_bounds__(512) void gemm_mfma(
        const ushort* __restrict__ A, const uint4* __restrict__ WTh4,
        const uint4* __restrict__ WTl4, const float* __restrict__ bias,
        void* __restrict__ outv, float* __restrict__ colsum, float* __restrict__ colsq,
        const float* __restrict__ onorm,
        const float* __restrict__ Wc, const float* __restrict__ bc, int n) {
    __shared__ uint4 sW[4096];   // hi | lo — 64 KB
    int tid = threadIdx.x;
    #pragma unroll
    for (int it = 0; it < 4; it++) {
        int j = it * 512 + tid;
        int nrow = j >> 4, c = j & 15;
        int sidx = nrow * 16 + (c ^ (nrow & 15));
        sW[sidx] = WTh4[j];
        sW[2048 + sidx] = WTl4[j];
    }
    __syncthreads();

    int wave = tid >> 6, lane = tid & 63;
    int l15 = lane & 15, quad = lane >> 4;
    int rbase = blockIdx.x * 128 + wave * 16;
    int arow = rbase + l15; if (arow > n - 1) arow = n - 1;

    bf16x8 af[4];
    #pragma unroll
    for (int kc = 0; kc < 4; kc++)
        af[kc] = *(const bf16x8*)(A + (size_t)arow * HN + kc * 32 + quad * 8);

    f32x4 acc[8];
    #pragma unroll
    for (int t = 0; t < 8; t++) acc[t] = (f32x4){0.f, 0.f, 0.f, 0.f};

    #pragma unroll
    for (int t = 0; t < 8; t++) {
        int nn = t * 16 + l15;
        int base = nn * 16, sw = nn & 15;
        #pragma unroll
        for (int kc = 0; kc < 4; kc++) {
            int c = kc * 4 + quad;
            bf16x8 bh = *(const bf16x8*)&sW[base + (c ^ sw)];
            acc[t] = __builtin_amdgcn_mfma_f32_16x16x32_bf16(af[kc], bh, acc[t], 0, 0, 0);
        }
        #pragma unroll
        for (int kc = 0; kc < 4; kc++) {
            int c = kc * 4 + quad;
            bf16x8 bl = *(const bf16x8*)&sW[2048 + base + (c ^ sw)];
            acc[t] = __builtin_amdgcn_mfma_f32_16x16x32_bf16(af[kc], bl, acc[t], 0, 0, 0);
        }
    }

    if (DO_CLS) {
        float bvt[8];
        #pragma unroll
        for (int t = 0; t < 8; t++) bvt[t] = bias[t * 16 + l15];
        #pragma unroll
        for (int c = 0; c < NC; c++) {
            float cl[4] = {0.f, 0.f, 0.f, 0.f};
            #pragma unroll
            for (int t = 0; t < 8; t++) {
                float wcv = Wc[(t * 16 + l15) * NC + c];
                #pragma unroll
                for (int i = 0; i < 4; i++) {
                    float v = acc[t][i] + bvt[t];
                    v = (v >= 0.f) ? v : SLOPEV * v;
                    cl[i] = fmaf(v, wcv, cl[i]);
                }
            }
            #pragma unroll
            for (int i = 0; i < 4; i++) {
                cl[i] += __shfl_xor(cl[i], 1);
                cl[i] += __shfl_xor(cl[i], 2);
                cl[i] += __shfl_xor(cl[i], 4);
                cl[i] += __shfl_xor(cl[i], 8);
            }
            if (l15 == 0) {
                float bcv = bc[c];
                #pragma unroll
                for (int i = 0; i < 4; i++) {
                    int row = rbase + quad * 4 + i;
                    if (row < n) ((float*)outv)[(size_t)row * NC + c] = cl[i] + bcv;
                }
            }
        }
        return;
    }

    float sarr[8], qarr[8];
    #pragma unroll
    for (int t = 0; t < 8; t++) {
        int col = t * 16 + l15;
        float bv = bias[col];
        float s = 0.f, q = 0.f;
        #pragma unroll
        for (int i = 0; i < 4; i++) {
            int row = rbase + quad * 4 + i;
            float v = acc[t][i] + bv;
            if (DO_LRELU) v = (v >= 0.f) ? v : SLOPEV * v;
            if (row < n) {
                if (DO_PACK) {
                    ((ushort*)outv)[(size_t)row * HN + col] = (ushort)bf16rne(v * onorm[row]);
                } else {
                    ((float*)outv)[(size_t)row * HN + col] = v;
                }
                if (DO_STATS) { s += v; q += v * v; }
            }
        }
        if (DO_STATS) {
            s += __shfl_xor(s, 16); q += __shfl_xor(q, 16);
            s += __shfl_xor(s, 32); q += __shfl_xor(q, 32);
        }
        sarr[t] = s; qarr[t] = q;
    }

    if (DO_STATS) {
        __syncthreads();
        float* sSum = (float*)sW;
        float* sSq  = (float*)sW + 1024;
        if (quad == 0) {
            #pragma unroll
            for (int t = 0; t < 8; t++) {
                sSum[wave * 128 + t * 16 + l15] = sarr[t];
                sSq [wave * 128 + t * 16 + l15] = qarr[t];
            }
        }
        __syncthreads();
        if (tid < 128) {
            float s = 0.f, q = 0.f;
            #pragma unroll
            for (int w = 0; w < 8; w++) { s += sSum[w * 128 + tid]; q += sSq[w * 128 + tid]; }
            atomicAdd(&colsum[tid], s);
            atomicAdd(&colsq[tid], q);
        }
    }
}

// ---------------- BN finalize ----------------
__global__ void bn_finalize(const float* __restrict__ colsum, const float* __restrict__ colsq,
                            const float* __restrict__ gamma, const float* __restrict__ beta,
                            float* __restrict__ scale, float* __restrict__ shift, int n) {
    int c = threadIdx.x;
    if (c < HN) {
        float inv = 1.f / (float)n;
        float mean = colsum[c] * inv;
        float var = colsq[c] * inv - mean * mean;
        if (var < 0.f) var = 0.f;
        float s = gamma[c] * rsqrtf(var + EPSV);
        scale[c] = s;
        shift[c] = beta[c] - mean * s;
    }
}

extern "C" void kernel_launch(void* const* d_in, const int* in_sizes, int n_in,
                              void* d_out, int out_size, void* d_ws, size_t ws_size,
                              hipStream_t stream) {
    const float* node_feat = (const float*)d_in[0];
    const int*   src    = (const int*)d_in[1];
    const int*   dst    = (const int*)d_in[2];
    const float* W1     = (const float*)d_in[3];
    const float* b1     = (const float*)d_in[4];
    const float* W2     = (const float*)d_in[5];
    const float* b2     = (const float*)d_in[6];
    const float* gamma1 = (const float*)d_in[7];
    const float* beta1  = (const float*)d_in[8];
    const float* gamma2 = (const float*)d_in[9];
    const float* beta2  = (const float*)d_in[10];
    const float* Wn1    = (const float*)d_in[11];
    const float* bn1    = (const float*)d_in[12];
    const float* Wn2    = (const float*)d_in[13];
    const float* bn2    = (const float*)d_in[14];
    const float* Wc     = (const float*)d_in[15];
    const float* bc     = (const float*)d_in[16];
    float* out = (float*)d_out;

    const int N = in_sizes[0] / HN;
    const int E = in_sizes[1];

    char* p = (char*)d_ws;
    float* bufA  = (float*)p; p += (size_t)N * HN * 4;   // lo: HbA(bf16), hi: Abf(bf16)
    float* bufB  = (float*)p; p += (size_t)N * HN * 4;   // fp32 gemm out / HbB(bf16)
    float* onorm = (float*)p; p += (size_t)N * 4;
    float* inorm = (float*)p; p += (size_t)N * 4;
    float* scale = (float*)p; p += HN * 4;
    float* shift = (float*)p; p += HN * 4;
    char* zbase = p;
    float* cs1 = (float*)p; p += HN * 4;
    float* cq1 = (float*)p; p += HN * 4;
    float* cs2 = (float*)p; p += HN * 4;
    float* cq2 = (float*)p; p += HN * 4;
    int* degO8 = (int*)p; p += (size_t)8 * N * 4;
    int* cntI  = (int*)p; p += (size_t)N * 4;
    size_t zbytes = (size_t)(p - zbase);
    int* row_ptr = (int*)p; p += (size_t)(N + 4) * 4;
    int* blockSums = (int*)p; p += 1024 * 4;
    int* rnk     = (int*)p; p += (size_t)E * 4;
    int* srcs    = (int*)p; p += (size_t)E * 4;
    ushort* WTh  = (ushort*)p; p += 4 * 16384 * 2;
    ushort* WTl  = (ushort*)p; p += 4 * 16384 * 2;
    if ((size_t)(p - (char*)d_ws) > ws_size) return;

    hipMemsetAsync(zbase, 0, zbytes, stream);

    int gE4 = (E + 1023) / 1024;
    int nb = (N + 1023) / 1024;
    rank_kernel<<<gE4, 256, 0, stream>>>(src, dst, degO8, cntI, rnk, E, N);
    scan_partial<<<nb, 256, 0, stream>>>(cntI, blockSums, N);
    scan_blocksums<<<1, 1024, 0, stream>>>(blockSums, nb);
    scan_final<<<nb, 256, 0, stream>>>(cntI, degO8, blockSums, row_ptr, onorm, inorm, N, E);
    scatter_kernel<<<gE4, 256, 0, stream>>>(src, dst, rnk, row_ptr, srcs, E);
    wprep_kernel<<<256, 256, 0, stream>>>(W1, W2, Wn1, Wn2, WTh, WTl);

    int gAgg = (N + 3) / 4;
    int gGemm = (N + 127) / 128;
    int gApply = (N * 32 + 255) / 256;

    ushort* HbA = (ushort*)bufA;
    ushort* Abf = (ushort*)bufA + (size_t)N * HN;
    ushort* HbB = (ushort*)bufB;

    // L1
    pack_kernel<<<gApply, 256, 0, stream>>>(node_feat, onorm, HbA, N * 32);
    agg_kernel<<<gAgg, 256, 0, stream>>>((const uint2*)HbA, (uint2*)Abf, srcs, row_ptr, inorm, N);
    gemm_mfma<1, 0, 0, 0><<<gGemm, 512, 0, stream>>>(Abf, (const uint4*)WTh, (const uint4*)WTl,
                                                     b1, bufB, cs1, cq1, nullptr, nullptr, nullptr, N);
    bn_finalize<<<1, 128, 0, stream>>>(cs1, cq1, gamma1, beta1, scale, shift, N);
    bnpack_kernel<<<gApply, 256, 0, stream>>>(bufB, HbA, scale, shift, onorm, N * 32);

    // L2
    agg_kernel<<<gAgg, 256, 0, stream>>>((const uint2*)HbA, (uint2*)Abf, srcs, row_ptr, inorm, N);
    gemm_mfma<1, 0, 0, 0><<<gGemm, 512, 0, stream>>>(Abf, (const uint4*)(WTh + 16384),
                                                     (const uint4*)(WTl + 16384),
                                                     b2, bufB, cs2, cq2, nullptr, nullptr, nullptr, N);
    bn_finalize<<<1, 128, 0, stream>>>(cs2, cq2, gamma2, beta2, scale, shift, N);
    bnpack_kernel<<<gApply, 256, 0, stream>>>(bufB, HbA, scale, shift, onorm, N * 32);

    // L3: gemm packs bf16*onorm directly
    agg_kernel<<<gAgg, 256, 0, stream>>>((const uint2*)HbA, (uint2*)Abf, srcs, row_ptr, inorm, N);
    gemm_mfma<0, 1, 1, 0><<<gGemm, 512, 0, stream>>>(Abf, (const uint4*)(WTh + 2 * 16384),
                                                     (const uint4*)(WTl + 2 * 16384),
                                                     bn1, HbB, nullptr, nullptr, onorm, nullptr, nullptr, N);

    // L4: gemm + fused lrelu + classifier -> d_out
    agg_kernel<<<gAgg, 256, 0, stream>>>((const uint2*)HbB, (uint2*)Abf, srcs, row_ptr, inorm, N);
    gemm_mfma<0, 0, 0, 1><<<gGemm, 512, 0, stream>>>(Abf, (const uint4*)(WTh + 3 * 16384),
                                                     (const uint4*)(WTl + 3 * 16384),
                                                     bn2, out, nullptr, nullptr, nullptr, Wc, bc, N);
}